// Round 8
// baseline (226.126 us; speedup 1.0000x reference)
//
#include <hip/hip_runtime.h>

#define N_NODES 100000
#define N_EDGES 1600000
#define NWIN 1024
#define WN 98                           // nodes per window; 1024*98 >= N
#define WCAP 4096                       // max edges per window (mean 1562)
#define CB ((N_EDGES + 4095) / 4096)    // 391 count blocks
#define FB ((N_EDGES + 16383) / 16384)  // 98 fill blocks
#define NTILES ((N_NODES + 63) / 64)    // 1563 row tiles of 64

__device__ __forceinline__ void fma4e(float4& a, const float4& x,
                                      const float4& w) {
  a.x = fmaf(x.x, w.x, a.x);
  a.y = fmaf(x.y, w.y, a.y);
  a.z = fmaf(x.z, w.z, a.z);
  a.w = fmaf(x.w, w.w, a.w);
}
__device__ __forceinline__ float hsum4(const float4& v) {
  return (v.x + v.y) + (v.z + v.w);
}

// ---------------------------------------------------------------------------
// Fused GEMM0+GEMM1, dot-product form (no transposes, swizzled W rows):
//   phase 1a: acc += X_tile   · Wr0   (k=0..63)
//   phase 1b: acc += AGG_tile · Wl0   (k=0..63)
//   h = relu(hsum(acc) + bl0*(deg>0))  -> kept in sX (LDS only)
//   phase 2 : h1 = h@Wl1.T + bl1 ; hr1 = h@Wr1.T
// sW[c][k]: row c's k-granule g stored at g^((c>>2)&15)  (bank-uniform)
// LDS = 2 * 64*68*4 = 34.8 KB -> 4 blocks/CU.
// ---------------------------------------------------------------------------
__global__ __launch_bounds__(256) void gemm01_kernel(
    const float* __restrict__ X, const float* __restrict__ AGG,
    const float* __restrict__ Wr0, const float* __restrict__ Wl0,
    const float* __restrict__ bl0, const unsigned* __restrict__ deg,
    const float* __restrict__ Wl1, const float* __restrict__ bl1,
    const float* __restrict__ Wr1, float* __restrict__ H1,
    float* __restrict__ HR1) {
  __shared__ float sW[64 * 68];
  __shared__ float sX[64 * 68];
  const int t = threadIdx.x;
  const int rbase = blockIdx.x * 64;
  const int tc = t & 15, tr = t >> 4;
  const int c0 = tc * 4, r0 = tr * 4;

  float4 a[4][4];
#pragma unroll
  for (int i = 0; i < 4; ++i)
#pragma unroll
    for (int j = 0; j < 4; ++j) a[i][j] = {0, 0, 0, 0};

#define STAGE_W64(Wp)                                      \
  {                                                        \
    const float4* W4 = (const float4*)(Wp);                \
    for (int f = t; f < 1024; f += 256) {                  \
      const int c = f >> 4, kq = f & 15;                   \
      const int g = kq ^ ((c >> 2) & 15);                  \
      *(float4*)&sW[c * 68 + (g << 2)] = W4[f];            \
    }                                                      \
  }

#define STAGE_X(Bp)                                        \
  {                                                        \
    const float4* B4 = (const float4*)(Bp);                \
    for (int f = t; f < 1024; f += 256) {                  \
      const int row = f >> 4, kq = f & 15;                 \
      const int grow = rbase + row;                        \
      float4 v = {0, 0, 0, 0};                             \
      if (grow < N_NODES) v = B4[(size_t)grow * 16 + kq];  \
      *(float4*)&sX[row * 68 + kq * 4] = v;                \
    }                                                      \
  }

#define DOT_ACCUM()                                                     \
  _Pragma("unroll 4") for (int kc = 0; kc < 64; kc += 4) {              \
    const int g = (kc >> 2) ^ tc;                                       \
    const float4 w0 = *(const float4*)&sW[(c0 + 0) * 68 + (g << 2)];    \
    const float4 w1 = *(const float4*)&sW[(c0 + 1) * 68 + (g << 2)];    \
    const float4 w2 = *(const float4*)&sW[(c0 + 2) * 68 + (g << 2)];    \
    const float4 w3 = *(const float4*)&sW[(c0 + 3) * 68 + (g << 2)];    \
    const float4 x0 = *(const float4*)&sX[(r0 + 0) * 68 + kc];          \
    const float4 x1 = *(const float4*)&sX[(r0 + 1) * 68 + kc];          \
    const float4 x2 = *(const float4*)&sX[(r0 + 2) * 68 + kc];          \
    const float4 x3 = *(const float4*)&sX[(r0 + 3) * 68 + kc];          \
    fma4e(a[0][0], x0, w0); fma4e(a[0][1], x0, w1);                     \
    fma4e(a[0][2], x0, w2); fma4e(a[0][3], x0, w3);                     \
    fma4e(a[1][0], x1, w0); fma4e(a[1][1], x1, w1);                     \
    fma4e(a[1][2], x1, w2); fma4e(a[1][3], x1, w3);                     \
    fma4e(a[2][0], x2, w0); fma4e(a[2][1], x2, w1);                     \
    fma4e(a[2][2], x2, w2); fma4e(a[2][3], x2, w3);                     \
    fma4e(a[3][0], x3, w0); fma4e(a[3][1], x3, w1);                     \
    fma4e(a[3][2], x3, w2); fma4e(a[3][3], x3, w3);                     \
  }

  // ---- phase 1a: X · Wr0 ----
  STAGE_W64(Wr0);
  STAGE_X(X);
  __syncthreads();
  DOT_ACCUM();
  __syncthreads();

  // ---- phase 1b: AGG · Wl0 ----
  STAGE_W64(Wl0);
  STAGE_X(AGG);
  __syncthreads();
  DOT_ACCUM();
  __syncthreads();

  // ---- epilogue 0: h into sX (LDS only); stage layer-1 weights ----
  {
    const float4 bias = *(const float4*)&bl0[c0];
#pragma unroll
    for (int i = 0; i < 4; ++i) {
      const int grow = rbase + r0 + i;
      const float gt = (grow < N_NODES && deg[grow] > 0) ? 1.0f : 0.0f;
      float4 h;
      h.x = fmaxf(hsum4(a[i][0]) + bias.x * gt, 0.0f);
      h.y = fmaxf(hsum4(a[i][1]) + bias.y * gt, 0.0f);
      h.z = fmaxf(hsum4(a[i][2]) + bias.z * gt, 0.0f);
      h.w = fmaxf(hsum4(a[i][3]) + bias.w * gt, 0.0f);
      *(float4*)&sX[(r0 + i) * 68 + c0] = h;
    }
  }
  {  // sW[c][k]: c<32 -> Wl1 row c; c>=32 -> Wr1 row c-32
    const float4* Wl4 = (const float4*)Wl1;
    const float4* Wr4 = (const float4*)Wr1;
    for (int f = t; f < 1024; f += 256) {
      const int c = f >> 4, kq = f & 15;
      const int g = kq ^ ((c >> 2) & 15);
      const float4 v = (c < 32) ? Wl4[c * 16 + kq] : Wr4[(c - 32) * 16 + kq];
      *(float4*)&sW[c * 68 + (g << 2)] = v;
    }
  }
#pragma unroll
  for (int i = 0; i < 4; ++i)
#pragma unroll
    for (int j = 0; j < 4; ++j) a[i][j] = {0, 0, 0, 0};
  __syncthreads();

  // ---- phase 2: h @ {Wl1|Wr1}.T ----
  DOT_ACCUM();

  const bool left = tc < 8;
  float4 bias = {0, 0, 0, 0};
  if (left) bias = *(const float4*)&bl1[c0];
#pragma unroll
  for (int i = 0; i < 4; ++i) {
    const int grow = rbase + r0 + i;
    if (grow < N_NODES) {
      float4 r;
      r.x = hsum4(a[i][0]) + bias.x;
      r.y = hsum4(a[i][1]) + bias.y;
      r.z = hsum4(a[i][2]) + bias.z;
      r.w = hsum4(a[i][3]) + bias.w;
      if (left)
        ((float4*)H1)[(size_t)grow * 8 + tc] = r;
      else
        ((float4*)HR1)[(size_t)grow * 8 + (tc - 8)] = r;
    }
  }
#undef STAGE_W64
#undef STAGE_X
#undef DOT_ACCUM
}

// ---------------------------------------------------------------------------
// Edge bucketing by dst window (1024 windows of 98 nodes).
// ---------------------------------------------------------------------------
__global__ __launch_bounds__(256) void bucket_count(const int* __restrict__ ei,
                                                    unsigned* __restrict__ bcnt) {
  __shared__ unsigned h[NWIN];
  const int t = threadIdx.x;
  for (int i = t; i < NWIN; i += 256) h[i] = 0;
  __syncthreads();
  const long long base = (long long)blockIdx.x * 4096;
#pragma unroll
  for (int i = 0; i < 16; ++i) {
    const long long e = base + i * 256 + t;
    if (e < N_EDGES) {
      const unsigned d = (unsigned)ei[N_EDGES + e];
      atomicAdd(&h[d / WN], 1u);
    }
  }
  __syncthreads();
  for (int i = t; i < NWIN; i += 256) {
    const unsigned c = h[i];
    if (c) atomicAdd(&bcnt[i], c);
  }
}

__global__ __launch_bounds__(1024) void bucket_scan(
    const unsigned* __restrict__ bcnt, unsigned* __restrict__ bbase,
    unsigned* __restrict__ bcursor) {
  __shared__ unsigned s[NWIN];
  const int t = threadIdx.x;
  const unsigned v = bcnt[t];
  s[t] = v;
  __syncthreads();
  for (int off = 1; off < NWIN; off <<= 1) {
    const unsigned u = (t >= off) ? s[t - off] : 0u;
    __syncthreads();
    s[t] += u;
    __syncthreads();
  }
  const unsigned ex = s[t] - v;
  bbase[t] = ex;
  bcursor[t] = ex;
  if (t == NWIN - 1) bbase[NWIN] = s[NWIN - 1];
}

// 16384 edges/block: LDS histogram -> bulk cursor reservation -> packed
// (dl<<24|src) writes in contiguous per-bucket chunks.
__global__ __launch_bounds__(256) void bucket_fill(const int* __restrict__ ei,
                                                   unsigned* __restrict__ bcursor,
                                                   unsigned* __restrict__ ebuf) {
  __shared__ unsigned lcnt[NWIN], gbase[NWIN];
  const int t = threadIdx.x;
  for (int i = t; i < NWIN; i += 256) lcnt[i] = 0;
  __syncthreads();
  const long long base = (long long)blockIdx.x * 16384;
#pragma unroll 4
  for (int i = 0; i < 64; ++i) {
    const long long e = base + i * 256 + t;
    if (e < N_EDGES) {
      const unsigned d = (unsigned)ei[N_EDGES + e];
      atomicAdd(&lcnt[d / WN], 1u);
    }
  }
  __syncthreads();
  for (int i = t; i < NWIN; i += 256) {
    const unsigned c = lcnt[i];
    gbase[i] = c ? atomicAdd(&bcursor[i], c) : 0u;
    lcnt[i] = 0;  // reused as local cursor
  }
  __syncthreads();
#pragma unroll 4
  for (int i = 0; i < 64; ++i) {
    const long long e = base + i * 256 + t;
    if (e < N_EDGES) {
      const unsigned s = (unsigned)ei[e];
      const unsigned d = (unsigned)ei[N_EDGES + e];
      const unsigned b = d / WN, dl = d - b * WN;
      const unsigned off = atomicAdd(&lcnt[b], 1u);
      ebuf[gbase[b] + off] = (dl << 24) | s;
    }
  }
}

// ---------------------------------------------------------------------------
// Per-window counting sort (in LDS, in-place in ebuf) -> CSR order.
// ---------------------------------------------------------------------------
__global__ __launch_bounds__(256) void win_sort(unsigned* __restrict__ ebuf,
                                                const unsigned* __restrict__ bbase,
                                                unsigned* __restrict__ rowptr,
                                                unsigned* __restrict__ deg) {
  __shared__ unsigned earr[WCAP];
  __shared__ unsigned sorted[WCAP];
  __shared__ unsigned hist[WN], pre[WN + 1], cur[WN];
  const int t = threadIdx.x, w = blockIdx.x;
  const int lo = w * WN;
  const unsigned beg = bbase[w], end = bbase[w + 1];
  const int n = (int)(end - beg);
  for (int i = t; i < WN; i += 256) hist[i] = 0;
  __syncthreads();
  for (int i = t; i < n; i += 256) {
    const unsigned p = ebuf[beg + i];
    earr[i] = p;
    atomicAdd(&hist[p >> 24], 1u);
  }
  __syncthreads();
  if (t == 0) {
    unsigned run = 0;
    for (int i = 0; i < WN; ++i) {
      pre[i] = run;
      run += hist[i];
    }
    pre[WN] = run;
  }
  __syncthreads();
  for (int dl = t; dl < WN; dl += 256) {
    const int node = lo + dl;
    if (node <= N_NODES) rowptr[node] = beg + pre[dl];
    if (node < N_NODES) deg[node] = hist[dl];
    cur[dl] = pre[dl];
  }
  __syncthreads();
  for (int i = t; i < n; i += 256) {
    const unsigned p = earr[i];
    const unsigned pos = atomicAdd(&cur[p >> 24], 1u);
    sorted[pos] = p;
  }
  __syncthreads();
  for (int i = t; i < n; i += 256) ebuf[beg + i] = sorted[i];
}

// ---------------------------------------------------------------------------
// Gather-aggregate (mean) + optional base add: one wave per dst node.
// Edge entries are packed (dl<<24|src) -> src = p & 0xFFFFFF.
// ---------------------------------------------------------------------------
template <int F, bool HAS_BASE>
__global__ __launch_bounds__(256) void gather_comb(
    const float* __restrict__ H, const unsigned* __restrict__ rowptr,
    const unsigned* __restrict__ csr, const float* __restrict__ base_row,
    float* __restrict__ outp) {
  constexpr int G = F / 4;
  constexpr int NG = 64 / G;
  const int node = (int)((blockIdx.x * 256 + threadIdx.x) >> 6);
  const int lane = threadIdx.x & 63;
  if (node >= N_NODES) return;
  const int g = lane / G, q = lane % G;
  const unsigned beg = rowptr[node], end = rowptr[node + 1];
  const float inv = (end > beg) ? 1.0f / (float)(end - beg) : 0.0f;
  const float4* __restrict__ H4 = (const float4*)H;

  float4 a0 = {0.f, 0.f, 0.f, 0.f}, a1 = {0.f, 0.f, 0.f, 0.f};
  unsigned e = beg + g;
  for (; e + NG < end; e += 2 * NG) {
    const unsigned s0 = csr[e] & 0xFFFFFFu, s1 = csr[e + NG] & 0xFFFFFFu;
    const float4 v0 = H4[(size_t)s0 * G + q];
    const float4 v1 = H4[(size_t)s1 * G + q];
    a0.x += v0.x; a0.y += v0.y; a0.z += v0.z; a0.w += v0.w;
    a1.x += v1.x; a1.y += v1.y; a1.z += v1.z; a1.w += v1.w;
  }
  if (e < end) {
    const float4 v = H4[(size_t)(csr[e] & 0xFFFFFFu) * G + q];
    a0.x += v.x; a0.y += v.y; a0.z += v.z; a0.w += v.w;
  }
  float sx = a0.x + a1.x, sy = a0.y + a1.y;
  float sz = a0.z + a1.z, sw = a0.w + a1.w;
#pragma unroll
  for (int m = G; m < 64; m <<= 1) {
    sx += __shfl_xor(sx, m, 64);
    sy += __shfl_xor(sy, m, 64);
    sz += __shfl_xor(sz, m, 64);
    sw += __shfl_xor(sw, m, 64);
  }
  if (g == 0) {
    float4 r;
    r.x = sx * inv; r.y = sy * inv; r.z = sz * inv; r.w = sw * inv;
    if (HAS_BASE) {
      const float4 b = ((const float4*)base_row)[(size_t)node * G + q];
      r.x += b.x; r.y += b.y; r.z += b.z; r.w += b.w;
    }
    ((float4*)outp)[(size_t)node * G + q] = r;
  }
}

extern "C" void kernel_launch(void* const* d_in, const int* in_sizes, int n_in,
                              void* d_out, int out_size, void* d_ws,
                              size_t ws_size, hipStream_t stream) {
  const float* x = (const float*)d_in[0];
  const int* ei = (const int*)d_in[1];
  const float* Wl0 = (const float*)d_in[2];
  const float* bl0 = (const float*)d_in[3];
  const float* Wr0 = (const float*)d_in[4];
  const float* Wl1 = (const float*)d_in[5];
  const float* bl1 = (const float*)d_in[6];
  const float* Wr1 = (const float*)d_in[7];
  float* out = (float*)d_out;

  const int N = N_NODES;

  // Workspace:
  //   aggx : N*64 f32
  //   bufB : h1 [N,32] + hr1 [N,32]
  //   deg[N], bcnt[1024], bbase[1025], bcursor[1024], rowptr[N+1], ebuf[E]
  float* aggx = (float*)d_ws;
  float* bufB = aggx + (size_t)N * 64;
  unsigned* deg = (unsigned*)(bufB + (size_t)N * 64);
  unsigned* bcnt = deg + N;
  unsigned* bbase = bcnt + NWIN;
  unsigned* bcursor = bbase + (NWIN + 1);
  unsigned* rowptr = bcursor + NWIN;
  unsigned* ebuf = rowptr + (N + 1);
  float* h1 = bufB;
  float* hr1 = bufB + (size_t)N * 32;

  hipMemsetAsync(bcnt, 0, NWIN * sizeof(unsigned), stream);

  const dim3 blk(256);

  // ---- edge bucketing + per-window counting sort -> CSR (both layers) ----
  bucket_count<<<CB, blk, 0, stream>>>(ei, bcnt);
  bucket_scan<<<1, NWIN, 0, stream>>>(bcnt, bbase, bcursor);
  bucket_fill<<<FB, blk, 0, stream>>>(ei, bcursor, ebuf);
  win_sort<<<NWIN, blk, 0, stream>>>(ebuf, bbase, rowptr, deg);

  // ---- layer-0 aggregation: aggx = mean(x[src]) ----
  gather_comb<64, false><<<(N * 64 + 255) / 256, blk, 0, stream>>>(
      x, rowptr, ebuf, nullptr, aggx);

  // ---- fused GEMMs: h in LDS; emits h1 = h@Wl1.T+bl1, hr1 = h@Wr1.T ----
  gemm01_kernel<<<NTILES, blk, 0, stream>>>(x, aggx, Wr0, Wl0, bl0, deg, Wl1,
                                            bl1, Wr1, h1, hr1);

  // ---- layer-1 aggregation + combine: out = mean(h1[src]) + hr1 ----
  gather_comb<32, true><<<(N * 64 + 255) / 256, blk, 0, stream>>>(
      h1, rowptr, ebuf, hr1, out);
}